// Round 6
// baseline (272.604 us; speedup 1.0000x reference)
//
#include <hip/hip_runtime.h>
#include <cstdint>
#include <cstddef>

typedef unsigned short u16;
typedef unsigned int u32;
typedef __attribute__((ext_vector_type(8))) short bf16x8;
typedef __attribute__((ext_vector_type(4))) float f32x4;
typedef __attribute__((ext_vector_type(16))) float f32x16;

__device__ __forceinline__ u16 f2bf(float f) {
  union { float f; unsigned int u; } v; v.f = f;
  unsigned int r = v.u + 0x7fffu + ((v.u >> 16) & 1u);
  return (u16)(r >> 16);
}

__device__ __forceinline__ u32 pack_bf_trunc(float hi, float lo) {
#if __has_builtin(__builtin_amdgcn_perm)
  return __builtin_amdgcn_perm(__float_as_uint(hi), __float_as_uint(lo), 0x07060302u);
#else
  return (__float_as_uint(hi) & 0xffff0000u) | (__float_as_uint(lo) >> 16);
#endif
}

__device__ __forceinline__ void glds16(const void* g, void* l) {
  __builtin_amdgcn_global_load_lds(
      (const __attribute__((address_space(1))) unsigned int*)g,
      (__attribute__((address_space(3))) unsigned int*)l, 16, 0, 0);
}

__device__ __forceinline__ f32x4 fzero4() { f32x4 z = {0.f, 0.f, 0.f, 0.f}; return z; }
__device__ __forceinline__ f32x16 fzero16() {
  f32x16 z;
  #pragma unroll
  for (int i = 0; i < 16; ++i) z[i] = 0.f;
  return z;
}

// ---------------- prep: cvt x,y -> bf16 AND transpose-convert weights ----------------
__global__ void prep_kernel(const float* __restrict__ x, u16* __restrict__ xb,
                            const float* __restrict__ y, u16* __restrict__ yb,
                            const float* __restrict__ Wq, const float* __restrict__ Wk,
                            const float* __restrict__ Wv, u16* __restrict__ wt) {
  __shared__ float tile[32][33];
  int bx = blockIdx.x;
  if (bx < 16384) {
    int i = bx * 256 + threadIdx.x;
    const float* src; u16* dst;
    if (i < 2097152) { src = x; dst = xb; }
    else             { src = y; dst = yb; i -= 2097152; }
    float4 v = ((const float4*)src)[i];
    ushort4 o = make_ushort4(f2bf(v.x), f2bf(v.y), f2bf(v.z), f2bf(v.w));
    ((ushort4*)dst)[i] = o;
    return;
  }
  int t = bx - 16384;
  const float* in; u16* out; int N, tn;
  if (t < 256)      { in = Wq; out = wt;              N = 256;  tn = t; }
  else if (t < 512) { in = Wk; out = wt + 256 * 1024; N = 256;  tn = t - 256; }
  else              { in = Wv; out = wt + 512 * 1024; N = 1024; tn = t - 512; }
  int ntiles = N >> 5;
  int n0 = (tn % ntiles) * 32, k0 = (tn / ntiles) * 32;
  int tx = threadIdx.x & 31, ty = threadIdx.x >> 5;
  #pragma unroll
  for (int j = ty; j < 32; j += 8) tile[j][tx] = in[(size_t)(k0 + j) * N + n0 + tx];
  __syncthreads();
  #pragma unroll
  for (int j = ty; j < 32; j += 8) out[(size_t)(n0 + j) * 1024 + k0 + tx] = f2bf(tile[tx][j]);
}

// ---------------- fused projection GEMM (BK=64, single-buffer, 4 blocks/CU) ------
// out tiles over [8192][1536]: cols 0-255 -> fb (Q, [b][h][m][32]),
// 256-511 -> gb (K, [b][h][nt][kc][128][8] fragment order),
// 512-1535 -> ht (V, [b][h][nt][mc][128][8] fragment order).
// Latency-bound regime: rely on inter-block TLP (4 blocks/CU) to hide stage drains.
__global__ __launch_bounds__(256, 4)
void gemm_all_kernel(const u16* __restrict__ xb, const u16* __restrict__ yb,
                     const u16* __restrict__ wt,
                     const float* __restrict__ bq, const float* __restrict__ bk,
                     const float* __restrict__ bv,
                     u16* __restrict__ fb, u16* __restrict__ gb, u16* __restrict__ ht) {
  __shared__ __align__(16) u16 ls[17408];   // 34.8 KB: staging (32 KB) / transpose (34.8 KB)
  u16* lA = ls;          // 8192 u16: A tile 128r x 64k, chunked [k/8][row]
  u16* lB = ls + 8192;   // 8192 u16: B tile
  const int tid = threadIdx.x, lane = tid & 63;
  const int quad = lane >> 4, l16 = lane & 15;
  const int wave = tid >> 6;

  // XCD-chunked swizzle (768 % 8 == 0 -> bijective): each XCD owns 8 contiguous row-panels
  int lin = blockIdx.x + 12 * blockIdx.y;
  lin = (lin & 7) * 96 + (lin >> 3);
  const int col0 = (lin % 12) * 128, row0 = (lin / 12) * 128;

  const int wm = (wave >> 1) * 64, wn = (wave & 1) * 64;
  const u16* A = (col0 < 256) ? xb : yb;

  f32x4 acc[4][4];
  #pragma unroll
  for (int i = 0; i < 4; i++)
    #pragma unroll
    for (int j = 0; j < 4; j++) acc[i][j] = fzero4();

  for (int k0 = 0; k0 < 1024; k0 += 64) {
    __syncthreads();
    #pragma unroll
    for (int i = 0; i < 4; i++) {
      int c = i * 256 + tid;
      glds16(A + (size_t)(row0 + (c & 127)) * 1024 + k0 + (c >> 7) * 8, lA + c * 8);
    }
    #pragma unroll
    for (int i = 0; i < 4; i++) {
      int c = i * 256 + tid;
      glds16(wt + (size_t)(col0 + (c & 127)) * 1024 + k0 + (c >> 7) * 8, lB + c * 8);
    }
    __syncthreads();
    #pragma unroll
    for (int kk = 0; kk < 2; kk++) {
      bf16x8 af[4], bfr[4];
      #pragma unroll
      for (int mi = 0; mi < 4; mi++)
        af[mi] = *(const bf16x8*)(lA + ((kk * 4 + quad) * 128 + wm + mi * 16 + l16) * 8);
      #pragma unroll
      for (int ni = 0; ni < 4; ni++)
        bfr[ni] = *(const bf16x8*)(lB + ((kk * 4 + quad) * 128 + wn + ni * 16 + l16) * 8);
      #pragma unroll
      for (int mi = 0; mi < 4; mi++)
        #pragma unroll
        for (int ni = 0; ni < 4; ni++)
          acc[mi][ni] = __builtin_amdgcn_mfma_f32_16x16x32_bf16(af[mi], bfr[ni], acc[mi][ni], 0, 0, 0);
    }
  }

  if (col0 < 512) {
    // Q / K epilogue: direct stores, fragment-friendly layouts
    #pragma unroll
    for (int mi = 0; mi < 4; mi++)
      #pragma unroll
      for (int ni = 0; ni < 4; ni++) {
        int col = col0 + wn + ni * 16 + l16;
        float bvv = (col < 256) ? bq[col] : bk[col - 256];
        #pragma unroll
        for (int r = 0; r < 4; r++) {
          int row = row0 + wm + mi * 16 + quad * 4 + r;
          float v = acc[mi][ni][r] + bvv;
          int bb = row >> 11, ml = row & 2047;
          if (col < 256) {
            int h = col >> 5, kk2 = col & 31;
            fb[(((size_t)(bb * 8 + h)) << 16) + ml * 32 + kk2] = f2bf(v);
          } else {
            int c2 = col - 256, h = c2 >> 5, kk2 = c2 & 31;
            gb[((((size_t)(bb * 8 + h)) * 16 + (ml >> 7)) << 12)
               + (kk2 >> 3) * 1024 + (ml & 127) * 8 + (kk2 & 7)] = f2bf(v);
          }
        }
      }
  } else {
    // V epilogue: transpose through LDS, write one contiguous 32KB tile [mc][dv][8]
    const int headblk = (col0 - 512) >> 7;
    const int bb = row0 >> 11, mloc0 = row0 & 2047;
    __syncthreads();  // staging reads done; reuse ls
    #pragma unroll
    for (int mi = 0; mi < 4; mi++)
      #pragma unroll
      for (int ni = 0; ni < 4; ni++) {
        int col = wn + ni * 16 + l16;             // block-local dv
        int rowl = wm + mi * 16 + quad * 4;       // block-local m
        float bvv = bv[(col0 - 512) + col];
        float v0 = acc[mi][ni][0] + bvv, v1 = acc[mi][ni][1] + bvv;
        float v2 = acc[mi][ni][2] + bvv, v3 = acc[mi][ni][3] + bvv;
        *(uint2*)(ls + col * 136 + rowl) =
            make_uint2(pack_bf_trunc(v1, v0), pack_bf_trunc(v3, v2));
      }
    __syncthreads();
    u16* tb = ht + ((((size_t)(bb * 8 + headblk)) * 16 + (mloc0 >> 7)) << 14);
    #pragma unroll
    for (int i = 0; i < 8; ++i) {
      int chunk = i * 256 + tid;                  // [mc=chunk>>7][dv=chunk&127]
      *(uint4*)(tb + chunk * 8) = *(const uint4*)(ls + (chunk & 127) * 136 + (chunk >> 7) * 8);
    }
  }
}

// ---------------- flash attention: 32x32 MFMA, KVBLK=64 half-tiles, 4 blocks/CU ----------------
__global__ __launch_bounds__(256, 4)
void attn_kernel(const u16* __restrict__ fb, const u16* __restrict__ gb,
                 const u16* __restrict__ ht, const float* __restrict__ x,
                 const float* __restrict__ gamma, float* __restrict__ out) {
  __shared__ __align__(16) u16 lK[2][2048];    // 2 x 4 KB : K half-tile [kc=4][n=64][8]
  __shared__ __align__(16) u16 lV[2][8192];    // 2 x 16 KB: V half-tile [mc=8][dv=128][8]
  const int tid = threadIdx.x;
  const int lane = tid & 63, wave = tid >> 6;
  const int hd = lane >> 5, l31 = lane & 31;

  // XCD-affine swizzle: hw linear id % 8 == head -> each XCD holds 4 (b,head) KV sets (2.56 MB, L2-fit)
  int lin = blockIdx.x + 16 * blockIdx.y + 128 * blockIdx.z;
  const int head = lin & 7;
  const int mblk = (lin >> 3) & 15;
  const int b = lin >> 7;
  const int m0 = mblk * 128;
  const int bh = b * 8 + head;

  const float sscale = 0.17677669529663687f * 1.4426950408889634f;  // 1/sqrt(32)*log2(e)

  // Q fragments: B-frag of mfma(K,Q): lane holds Q[m=l31][k = ks*16 + hd*8 + j]
  const int qrow = m0 + wave * 32 + l31;
  union { bf16x8 v; u16 s[8]; } q0, q1;
  {
    const u16* qp = fb + (((size_t)bh * 2048 + qrow) << 5);
    q0.v = *(const bf16x8*)(qp + hd * 8);
    q1.v = *(const bf16x8*)(qp + 16 + hd * 8);
    #pragma unroll
    for (int j = 0; j < 8; ++j) {
      q0.s[j] = f2bf(__uint_as_float((u32)q0.s[j] << 16) * sscale);
      q1.s[j] = f2bf(__uint_as_float((u32)q1.s[j] << 16) * sscale);
    }
  }

  f32x16 oacc[4];
  #pragma unroll
  for (int i = 0; i < 4; ++i) oacc[i] = fzero16();
  float lsacc[4] = {0.f, 0.f, 0.f, 0.f};       // 4 independent sum chains (all indices static)

  const u16* kbase = gb + ((size_t)bh << 16);
  const u16* vbase = ht + ((size_t)bh << 18);

  // stage one 64-row half-tile (t = 0..31): K 4 KB + V 16 KB
  auto stage = [&](int bufsel, int t) {
    const int nt = t >> 1, half = t & 1;
    const u16* ks_ = kbase + ((size_t)nt << 12) + (half << 9);    // + half*64 rows * 8
    const u16* vs_ = vbase + ((size_t)nt << 14) + (half << 13);   // + half*8 mc * 1024
    glds16(ks_ + (tid >> 6) * 1024 + (tid & 63) * 8, &lK[bufsel][tid * 8]);
    #pragma unroll
    for (int i = 0; i < 4; ++i) {
      int c = i * 256 + tid;
      glds16(vs_ + (c >> 7) * 1024 + (c & 127) * 8, &lV[bufsel][c * 8]);
    }
  };

  // one 64-n half-tile compute: QK^T -> leaky -> exp2 -> pack -> permlane swap -> PV
  auto compute = [&](const u16* Kc, const u16* Vc) {
    // S^T = K·Q^T per 32-row n-tile; D: col=m=l31, row(n) = (reg&3)+8*(reg>>2)+4*hd
    u32 pk[2][8];
    #pragma unroll
    for (int nt4 = 0; nt4 < 2; ++nt4) {
      bf16x8 k0 = *(const bf16x8*)(Kc + hd * 512 + (nt4 * 32 + l31) * 8);
      bf16x8 k1 = *(const bf16x8*)(Kc + (2 + hd) * 512 + (nt4 * 32 + l31) * 8);
      __builtin_amdgcn_s_setprio(1);
      f32x16 s = __builtin_amdgcn_mfma_f32_32x32x16_bf16(k0, q0.v, fzero16(), 0, 0, 0);
      s = __builtin_amdgcn_mfma_f32_32x32x16_bf16(k1, q1.v, s, 0, 0, 0);
      __builtin_amdgcn_s_setprio(0);
      float p[16];
      #pragma unroll
      for (int r = 0; r < 16; ++r) {
        float sv = s[r];
        float lv = fmaxf(sv, 0.2f * sv);            // leaky-relu (scale pre-folded into Q)
        p[r] = __builtin_amdgcn_exp2f(lv);
        lsacc[r & 3] += p[r];                       // static index: 4 parallel chains
      }
      #pragma unroll
      for (int s2 = 0; s2 < 4; ++s2) {              // pack pairs (n even, n odd)
        pk[nt4][s2 * 2 + 0] = pack_bf_trunc(p[s2 * 4 + 1], p[s2 * 4 + 0]);
        pk[nt4][s2 * 2 + 1] = pack_bf_trunc(p[s2 * 4 + 3], p[s2 * 4 + 2]);
      }
    }

    // PV: A-frag P[m=l31][n = kt*16 + hd*8 + j] assembled via v_permlane32_swap_b32 (T12)
    #pragma unroll
    for (int kt = 0; kt < 4; ++kt) {
      const int nt4 = kt >> 1, a = kt & 1;
      u32 w0 = pk[nt4][a * 4 + 0], w1 = pk[nt4][a * 4 + 1];   // s2=2a   pairs (rows 16a+4hd+{0..3})
      u32 w2 = pk[nt4][a * 4 + 2], w3 = pk[nt4][a * 4 + 3];   // s2=2a+1 pairs (rows 16a+8+4hd+{0..3})
      // after swap: w0/w1 = frag words 0/1 (n=16a+8hd+{0..3}), w2/w3 = words 2/3 (+4..7)
      asm("v_permlane32_swap_b32 %0, %1" : "+v"(w0), "+v"(w2));
      asm("v_permlane32_swap_b32 %0, %1" : "+v"(w1), "+v"(w3));
      union { u32 w[4]; bf16x8 v; } pf;
      pf.w[0] = w0; pf.w[1] = w1; pf.w[2] = w2; pf.w[3] = w3;
      __builtin_amdgcn_s_setprio(1);
      #pragma unroll
      for (int dvt = 0; dvt < 4; ++dvt) {
        bf16x8 vf = *(const bf16x8*)(Vc + ((kt * 2 + hd) * 128 + dvt * 32 + l31) * 8);
        oacc[dvt] = __builtin_amdgcn_mfma_f32_32x32x16_bf16(pf.v, vf, oacc[dvt], 0, 0, 0);
      }
      __builtin_amdgcn_s_setprio(0);
    }
  };

  stage(0, 0);
  __syncthreads();

  #pragma unroll 1
  for (int it = 0; it < 32; it += 2) {
    stage(1, it + 1);                  // prefetch odd half-tile; drained by barrier below
    compute(&lK[0][0], &lV[0][0]);
    __syncthreads();                   // prefetch landed; buf1 ready
    if (it + 2 < 32) stage(0, it + 2); // prefetch next even half-tile
    compute(&lK[1][0], &lV[1][0]);
    __syncthreads();
  }

  // row sums: lane holds partial over its n-subset for row m=l31; partner holds the rest
  float lsum = (lsacc[0] + lsacc[1]) + (lsacc[2] + lsacc[3]);
  float ltot = lsum + __shfl_xor(lsum, 32, 64);
  float inv = 1.0f / ltot;
  const float gam = gamma[0];
  const size_t rowbase = ((size_t)(b * 2048 + m0 + wave * 32)) * 1024 + head * 128 + l31;
  #pragma unroll
  for (int reg = 0; reg < 16; ++reg) {
    const int m32 = (reg & 3) + 8 * (reg >> 2) + 4 * hd;
    float iv = __shfl(inv, m32, 64);
    #pragma unroll
    for (int dvt = 0; dvt < 4; ++dvt) {
      size_t idx = rowbase + (size_t)m32 * 1024 + dvt * 32;
      out[idx] = gam * (oacc[dvt][reg] * iv) + x[idx];
    }
  }
}

extern "C" void kernel_launch(void* const* d_in, const int* in_sizes, int n_in,
                              void* d_out, int out_size, void* d_ws, size_t ws_size,
                              hipStream_t stream) {
  const float* x     = (const float*)d_in[0];
  const float* y     = (const float*)d_in[1];
  const float* Wq    = (const float*)d_in[2];
  const float* bq    = (const float*)d_in[3];
  const float* Wk    = (const float*)d_in[4];
  const float* bk    = (const float*)d_in[5];
  const float* Wv    = (const float*)d_in[6];
  const float* bv    = (const float*)d_in[7];
  const float* gamma = (const float*)d_in[8];
  float* out = (float*)d_out;

  char* ws = (char*)d_ws;
  u16* xb = (u16*)(ws);                 // 16 MB  [B*M][1024]
  u16* yb = (u16*)(ws + 16777216);      // 16 MB
  u16* wt = (u16*)(ws + 33554432);      // 3 MB   [1536][1024]  (Wq^T|Wk^T|Wv^T)
  u16* fb = (u16*)(ws + 36700160);      // 4 MB   Q  [b][h][m][32]
  u16* gb = (u16*)(ws + 40894464);      // 4 MB   K  [b][h][nt][kc][128][8]
  u16* ht = (u16*)(ws + 45088768);      // 16 MB  V  [b][h][nt][mc][128][8]

  prep_kernel<<<16384 + 1536, 256, 0, stream>>>(x, xb, y, yb, Wq, Wk, Wv, wt);
  gemm_all_kernel<<<dim3(12, 64), 256, 0, stream>>>(xb, yb, wt, bq, bk, bv, fb, gb, ht);
  attn_kernel<<<dim3(16, 8, 4), 256, 0, stream>>>(fb, gb, ht, x, gamma, out);
}

// Round 7
// 237.823 us; speedup vs baseline: 1.1462x; 1.1462x over previous
//
#include <hip/hip_runtime.h>
#include <cstdint>
#include <cstddef>

typedef unsigned short u16;
typedef unsigned int u32;
typedef __attribute__((ext_vector_type(8))) short bf16x8;
typedef __attribute__((ext_vector_type(4))) float f32x4;
typedef __attribute__((ext_vector_type(16))) float f32x16;

__device__ __forceinline__ u16 f2bf(float f) {
  union { float f; unsigned int u; } v; v.f = f;
  unsigned int r = v.u + 0x7fffu + ((v.u >> 16) & 1u);
  return (u16)(r >> 16);
}

__device__ __forceinline__ u32 pack_bf_trunc(float hi, float lo) {
#if __has_builtin(__builtin_amdgcn_perm)
  return __builtin_amdgcn_perm(__float_as_uint(hi), __float_as_uint(lo), 0x07060302u);
#else
  return (__float_as_uint(hi) & 0xffff0000u) | (__float_as_uint(lo) >> 16);
#endif
}

__device__ __forceinline__ void glds16(const void* g, void* l) {
  __builtin_amdgcn_global_load_lds(
      (const __attribute__((address_space(1))) unsigned int*)g,
      (__attribute__((address_space(3))) unsigned int*)l, 16, 0, 0);
}

__device__ __forceinline__ f32x4 fzero4() { f32x4 z = {0.f, 0.f, 0.f, 0.f}; return z; }
__device__ __forceinline__ f32x16 fzero16() {
  f32x16 z;
  #pragma unroll
  for (int i = 0; i < 16; ++i) z[i] = 0.f;
  return z;
}

// ---------------- prep: grid-stride cvt x,y -> bf16 + transpose-convert weights ----------------
// 2048 grid-stride convert blocks (8 float4/thread) + 512 transpose blocks (3 tiles each).
// Old version used 17920 one-float4-per-thread blocks -> dispatch-overhead-bound.
__global__ __launch_bounds__(256)
void prep_kernel(const float* __restrict__ x, u16* __restrict__ xb,
                 const float* __restrict__ y, u16* __restrict__ yb,
                 const float* __restrict__ Wq, const float* __restrict__ Wk,
                 const float* __restrict__ Wv, u16* __restrict__ wt) {
  __shared__ float tile[32][33];
  int bx = blockIdx.x;
  if (bx < 2048) {
    // x: 2097152 float4, y: 2097152 float4
    #pragma unroll 2
    for (int i = bx * 256 + threadIdx.x; i < 4194304; i += 2048 * 256) {
      const float* src; u16* dst; int j = i;
      if (j < 2097152) { src = x; dst = xb; }
      else             { src = y; dst = yb; j -= 2097152; }
      float4 v = ((const float4*)src)[j];
      ((ushort4*)dst)[j] = make_ushort4(f2bf(v.x), f2bf(v.y), f2bf(v.z), f2bf(v.w));
    }
    return;
  }
  int tb = bx - 2048;                       // 0..511, each handles 3 weight tiles
  for (int t = tb; t < 1536; t += 512) {
    const float* in; u16* out; int N, tn;
    if (t < 256)      { in = Wq; out = wt;              N = 256;  tn = t; }
    else if (t < 512) { in = Wk; out = wt + 256 * 1024; N = 256;  tn = t - 256; }
    else              { in = Wv; out = wt + 512 * 1024; N = 1024; tn = t - 512; }
    int ntiles = N >> 5;
    int n0 = (tn % ntiles) * 32, k0 = (tn / ntiles) * 32;
    int tx = threadIdx.x & 31, ty = threadIdx.x >> 5;
    __syncthreads();                        // protect tile from previous iteration's readers
    #pragma unroll
    for (int j = ty; j < 32; j += 8) tile[j][tx] = in[(size_t)(k0 + j) * N + n0 + tx];
    __syncthreads();
    #pragma unroll
    for (int j = ty; j < 32; j += 8) out[(size_t)(n0 + j) * 1024 + k0 + tx] = f2bf(tile[tx][j]);
  }
}

// ---------------- fused projection GEMM (BK=64, single-buffer, 4 blocks/CU) ------
// out tiles over [8192][1536]: cols 0-255 -> fb (Q, [b][h][m][32]),
// 256-511 -> gb (K, [b][h][nt][kc][128][8] fragment order),
// 512-1535 -> ht (V, [b][h][nt][mc][128][8] fragment order).
// Latency-bound regime: rely on inter-block TLP (4 blocks/CU) to hide stage drains.
__global__ __launch_bounds__(256, 4)
void gemm_all_kernel(const u16* __restrict__ xb, const u16* __restrict__ yb,
                     const u16* __restrict__ wt,
                     const float* __restrict__ bq, const float* __restrict__ bk,
                     const float* __restrict__ bv,
                     u16* __restrict__ fb, u16* __restrict__ gb, u16* __restrict__ ht) {
  __shared__ __align__(16) u16 ls[17408];   // 34.8 KB: staging (32 KB) / transpose (34.8 KB)
  u16* lA = ls;          // 8192 u16: A tile 128r x 64k, chunked [k/8][row]
  u16* lB = ls + 8192;   // 8192 u16: B tile
  const int tid = threadIdx.x, lane = tid & 63;
  const int quad = lane >> 4, l16 = lane & 15;
  const int wave = tid >> 6;

  // XCD-chunked swizzle (768 % 8 == 0 -> bijective): each XCD owns 8 contiguous row-panels
  int lin = blockIdx.x + 12 * blockIdx.y;
  lin = (lin & 7) * 96 + (lin >> 3);
  const int col0 = (lin % 12) * 128, row0 = (lin / 12) * 128;

  const int wm = (wave >> 1) * 64, wn = (wave & 1) * 64;
  const u16* A = (col0 < 256) ? xb : yb;

  f32x4 acc[4][4];
  #pragma unroll
  for (int i = 0; i < 4; i++)
    #pragma unroll
    for (int j = 0; j < 4; j++) acc[i][j] = fzero4();

  for (int k0 = 0; k0 < 1024; k0 += 64) {
    __syncthreads();
    #pragma unroll
    for (int i = 0; i < 4; i++) {
      int c = i * 256 + tid;
      glds16(A + (size_t)(row0 + (c & 127)) * 1024 + k0 + (c >> 7) * 8, lA + c * 8);
    }
    #pragma unroll
    for (int i = 0; i < 4; i++) {
      int c = i * 256 + tid;
      glds16(wt + (size_t)(col0 + (c & 127)) * 1024 + k0 + (c >> 7) * 8, lB + c * 8);
    }
    __syncthreads();
    #pragma unroll
    for (int kk = 0; kk < 2; kk++) {
      bf16x8 af[4], bfr[4];
      #pragma unroll
      for (int mi = 0; mi < 4; mi++)
        af[mi] = *(const bf16x8*)(lA + ((kk * 4 + quad) * 128 + wm + mi * 16 + l16) * 8);
      #pragma unroll
      for (int ni = 0; ni < 4; ni++)
        bfr[ni] = *(const bf16x8*)(lB + ((kk * 4 + quad) * 128 + wn + ni * 16 + l16) * 8);
      #pragma unroll
      for (int mi = 0; mi < 4; mi++)
        #pragma unroll
        for (int ni = 0; ni < 4; ni++)
          acc[mi][ni] = __builtin_amdgcn_mfma_f32_16x16x32_bf16(af[mi], bfr[ni], acc[mi][ni], 0, 0, 0);
    }
  }

  if (col0 < 512) {
    // Q / K epilogue: direct stores, fragment-friendly layouts
    #pragma unroll
    for (int mi = 0; mi < 4; mi++)
      #pragma unroll
      for (int ni = 0; ni < 4; ni++) {
        int col = col0 + wn + ni * 16 + l16;
        float bvv = (col < 256) ? bq[col] : bk[col - 256];
        #pragma unroll
        for (int r = 0; r < 4; r++) {
          int row = row0 + wm + mi * 16 + quad * 4 + r;
          float v = acc[mi][ni][r] + bvv;
          int bb = row >> 11, ml = row & 2047;
          if (col < 256) {
            int h = col >> 5, kk2 = col & 31;
            fb[(((size_t)(bb * 8 + h)) << 16) + ml * 32 + kk2] = f2bf(v);
          } else {
            int c2 = col - 256, h = c2 >> 5, kk2 = c2 & 31;
            gb[((((size_t)(bb * 8 + h)) * 16 + (ml >> 7)) << 12)
               + (kk2 >> 3) * 1024 + (ml & 127) * 8 + (kk2 & 7)] = f2bf(v);
          }
        }
      }
  } else {
    // V epilogue: transpose through LDS, write one contiguous 32KB tile [mc][dv][8]
    const int headblk = (col0 - 512) >> 7;
    const int bb = row0 >> 11, mloc0 = row0 & 2047;
    __syncthreads();  // staging reads done; reuse ls
    #pragma unroll
    for (int mi = 0; mi < 4; mi++)
      #pragma unroll
      for (int ni = 0; ni < 4; ni++) {
        int col = wn + ni * 16 + l16;             // block-local dv
        int rowl = wm + mi * 16 + quad * 4;       // block-local m
        float bvv = bv[(col0 - 512) + col];
        float v0 = acc[mi][ni][0] + bvv, v1 = acc[mi][ni][1] + bvv;
        float v2 = acc[mi][ni][2] + bvv, v3 = acc[mi][ni][3] + bvv;
        *(uint2*)(ls + col * 136 + rowl) =
            make_uint2(pack_bf_trunc(v1, v0), pack_bf_trunc(v3, v2));
      }
    __syncthreads();
    u16* tb = ht + ((((size_t)(bb * 8 + headblk)) * 16 + (mloc0 >> 7)) << 14);
    #pragma unroll
    for (int i = 0; i < 8; ++i) {
      int chunk = i * 256 + tid;                  // [mc=chunk>>7][dv=chunk&127]
      *(uint4*)(tb + chunk * 8) = *(const uint4*)(ls + (chunk & 127) * 136 + (chunk >> 7) * 8);
    }
  }
}

// ---------------- flash attention: 32x32 MFMA, KVBLK=128 (round-4 proven), dbuf ----------------
__global__ __launch_bounds__(256, 2)
void attn_kernel(const u16* __restrict__ fb, const u16* __restrict__ gb,
                 const u16* __restrict__ ht, const float* __restrict__ x,
                 const float* __restrict__ gamma, float* __restrict__ out) {
  __shared__ __align__(16) u16 lK[2][4096];    // 2 x 8 KB : K tile [kc=4][n=128][8]
  __shared__ __align__(16) u16 lV[2][16384];   // 2 x 32 KB: V tile [mc=16][dv=128][8]
  const int tid = threadIdx.x;
  const int lane = tid & 63, wave = tid >> 6;
  const int hd = lane >> 5, l31 = lane & 31;

  // XCD-affine swizzle: hw linear id % 8 == head -> each XCD holds 4 (b,head) KV sets (2.56 MB, L2-fit)
  int lin = blockIdx.x + 16 * blockIdx.y + 128 * blockIdx.z;
  const int head = lin & 7;
  const int mblk = (lin >> 3) & 15;
  const int b = lin >> 7;
  const int m0 = mblk * 128;
  const int bh = b * 8 + head;

  const float sscale = 0.17677669529663687f * 1.4426950408889634f;  // 1/sqrt(32)*log2(e)

  // Q fragments: B-frag of mfma(K,Q): lane holds Q[m=l31][k = ks*16 + hd*8 + j]
  const int qrow = m0 + wave * 32 + l31;
  union { bf16x8 v; u16 s[8]; } q0, q1;
  {
    const u16* qp = fb + (((size_t)bh * 2048 + qrow) << 5);
    q0.v = *(const bf16x8*)(qp + hd * 8);
    q1.v = *(const bf16x8*)(qp + 16 + hd * 8);
    #pragma unroll
    for (int j = 0; j < 8; ++j) {
      q0.s[j] = f2bf(__uint_as_float((u32)q0.s[j] << 16) * sscale);
      q1.s[j] = f2bf(__uint_as_float((u32)q1.s[j] << 16) * sscale);
    }
  }

  f32x16 oacc[4];
  #pragma unroll
  for (int i = 0; i < 4; ++i) oacc[i] = fzero16();
  float lsacc[4] = {0.f, 0.f, 0.f, 0.f};       // 4 independent sum chains (static indices)

  const u16* kbase = gb + ((size_t)bh << 16);
  const u16* vbase = ht + ((size_t)bh << 18);

  auto stage = [&](int bufsel, int nt) {
    const u16* ks_ = kbase + ((size_t)nt << 12);
    const u16* vs_ = vbase + ((size_t)nt << 14);
    #pragma unroll
    for (int i = 0; i < 2; ++i) glds16(ks_ + (i * 256 + tid) * 8, &lK[bufsel][(i * 256 + tid) * 8]);
    #pragma unroll
    for (int i = 0; i < 8; ++i) glds16(vs_ + (i * 256 + tid) * 8, &lV[bufsel][(i * 256 + tid) * 8]);
  };

  // one KV-tile (128 n) compute: QK^T -> leaky -> exp2 -> pack -> permlane swap -> PV
  auto compute = [&](const u16* Kc, const u16* Vc) {
    // S^T = K·Q^T per 32-row n-tile; D: col=m=l31, row(n) = (reg&3)+8*(reg>>2)+4*hd
    u32 pk[4][8];
    #pragma unroll
    for (int nt4 = 0; nt4 < 4; ++nt4) {
      bf16x8 k0 = *(const bf16x8*)(Kc + hd * 1024 + (nt4 * 32 + l31) * 8);
      bf16x8 k1 = *(const bf16x8*)(Kc + (2 + hd) * 1024 + (nt4 * 32 + l31) * 8);
      __builtin_amdgcn_s_setprio(1);
      f32x16 s = __builtin_amdgcn_mfma_f32_32x32x16_bf16(k0, q0.v, fzero16(), 0, 0, 0);
      s = __builtin_amdgcn_mfma_f32_32x32x16_bf16(k1, q1.v, s, 0, 0, 0);
      __builtin_amdgcn_s_setprio(0);
      float p[16];
      #pragma unroll
      for (int r = 0; r < 16; ++r) {
        float sv = s[r];
        float lv = fmaxf(sv, 0.2f * sv);            // leaky-relu (scale pre-folded into Q)
        p[r] = __builtin_amdgcn_exp2f(lv);
        lsacc[r & 3] += p[r];                       // 4 parallel dependency chains
      }
      #pragma unroll
      for (int s2 = 0; s2 < 4; ++s2) {              // pack pairs (n even, n odd)
        pk[nt4][s2 * 2 + 0] = pack_bf_trunc(p[s2 * 4 + 1], p[s2 * 4 + 0]);
        pk[nt4][s2 * 2 + 1] = pack_bf_trunc(p[s2 * 4 + 3], p[s2 * 4 + 2]);
      }
    }

    // PV: A-frag P[m=l31][n = kt*16 + hd*8 + j] assembled via v_permlane32_swap_b32 (T12)
    #pragma unroll
    for (int kt = 0; kt < 8; ++kt) {
      const int nt4 = kt >> 1, a = kt & 1;
      u32 w0 = pk[nt4][a * 4 + 0], w1 = pk[nt4][a * 4 + 1];   // s2=2a   pairs (rows 16a+4hd+{0..3})
      u32 w2 = pk[nt4][a * 4 + 2], w3 = pk[nt4][a * 4 + 3];   // s2=2a+1 pairs (rows 16a+8+4hd+{0..3})
      // after swap: w0/w1 = frag words 0/1 (n=16a+8hd+{0..3}), w2/w3 = words 2/3 (+4..7)
      asm("v_permlane32_swap_b32 %0, %1" : "+v"(w0), "+v"(w2));
      asm("v_permlane32_swap_b32 %0, %1" : "+v"(w1), "+v"(w3));
      union { u32 w[4]; bf16x8 v; } pf;
      pf.w[0] = w0; pf.w[1] = w1; pf.w[2] = w2; pf.w[3] = w3;
      __builtin_amdgcn_s_setprio(1);
      #pragma unroll
      for (int dvt = 0; dvt < 4; ++dvt) {
        bf16x8 vf = *(const bf16x8*)(Vc + (kt * 2 + hd) * 1024 + (dvt * 32 + l31) * 8);
        oacc[dvt] = __builtin_amdgcn_mfma_f32_32x32x16_bf16(pf.v, vf, oacc[dvt], 0, 0, 0);
      }
      __builtin_amdgcn_s_setprio(0);
    }
  };

  stage(0, 0);
  __syncthreads();

  #pragma unroll 1
  for (int it = 0; it < 16; it += 2) {
    stage(1, it + 1);                  // prefetch odd tile; drained by barrier below
    compute(&lK[0][0], &lV[0][0]);
    __syncthreads();                   // prefetch landed; buf1 ready
    if (it + 2 < 16) stage(0, it + 2); // prefetch next even tile
    compute(&lK[1][0], &lV[1][0]);
    __syncthreads();
  }

  // row sums: lane holds partial over its n-subset for row m=l31; partner holds the rest
  float lsum = (lsacc[0] + lsacc[1]) + (lsacc[2] + lsacc[3]);
  float ltot = lsum + __shfl_xor(lsum, 32, 64);
  float inv = 1.0f / ltot;
  const float gam = gamma[0];
  const size_t rowbase = ((size_t)(b * 2048 + m0 + wave * 32)) * 1024 + head * 128 + l31;
  #pragma unroll
  for (int reg = 0; reg < 16; ++reg) {
    const int m32 = (reg & 3) + 8 * (reg >> 2) + 4 * hd;
    float iv = __shfl(inv, m32, 64);
    #pragma unroll
    for (int dvt = 0; dvt < 4; ++dvt) {
      size_t idx = rowbase + (size_t)m32 * 1024 + dvt * 32;
      out[idx] = gam * (oacc[dvt][reg] * iv) + x[idx];
    }
  }
}

extern "C" void kernel_launch(void* const* d_in, const int* in_sizes, int n_in,
                              void* d_out, int out_size, void* d_ws, size_t ws_size,
                              hipStream_t stream) {
  const float* x     = (const float*)d_in[0];
  const float* y     = (const float*)d_in[1];
  const float* Wq    = (const float*)d_in[2];
  const float* bq    = (const float*)d_in[3];
  const float* Wk    = (const float*)d_in[4];
  const float* bk    = (const float*)d_in[5];
  const float* Wv    = (const float*)d_in[6];
  const float* bv    = (const float*)d_in[7];
  const float* gamma = (const float*)d_in[8];
  float* out = (float*)d_out;

  char* ws = (char*)d_ws;
  u16* xb = (u16*)(ws);                 // 16 MB  [B*M][1024]
  u16* yb = (u16*)(ws + 16777216);      // 16 MB
  u16* wt = (u16*)(ws + 33554432);      // 3 MB   [1536][1024]  (Wq^T|Wk^T|Wv^T)
  u16* fb = (u16*)(ws + 36700160);      // 4 MB   Q  [b][h][m][32]
  u16* gb = (u16*)(ws + 40894464);      // 4 MB   K  [b][h][nt][kc][128][8]
  u16* ht = (u16*)(ws + 45088768);      // 16 MB  V  [b][h][nt][mc][128][8]

  prep_kernel<<<2560, 256, 0, stream>>>(x, xb, y, yb, Wq, Wk, Wv, wt);
  gemm_all_kernel<<<dim3(12, 64), 256, 0, stream>>>(xb, yb, wt, bq, bk, bv, fb, gb, ht);
  attn_kernel<<<dim3(16, 8, 4), 256, 0, stream>>>(fb, gb, ht, x, gamma, out);
}

// Round 8
// 234.151 us; speedup vs baseline: 1.1642x; 1.0157x over previous
//
#include <hip/hip_runtime.h>
#include <cstdint>
#include <cstddef>

typedef unsigned short u16;
typedef unsigned int u32;
typedef __attribute__((ext_vector_type(8))) short bf16x8;
typedef __attribute__((ext_vector_type(4))) float f32x4;
typedef __attribute__((ext_vector_type(16))) float f32x16;

__device__ __forceinline__ u16 f2bf(float f) {
  union { float f; unsigned int u; } v; v.f = f;
  unsigned int r = v.u + 0x7fffu + ((v.u >> 16) & 1u);
  return (u16)(r >> 16);
}

__device__ __forceinline__ u32 pack_bf_trunc(float hi, float lo) {
#if __has_builtin(__builtin_amdgcn_perm)
  return __builtin_amdgcn_perm(__float_as_uint(hi), __float_as_uint(lo), 0x07060302u);
#else
  return (__float_as_uint(hi) & 0xffff0000u) | (__float_as_uint(lo) >> 16);
#endif
}

__device__ __forceinline__ u32 cvt_pk_bf16(float lo, float hi) {
  u32 r;
  asm("v_cvt_pk_bf16_f32 %0, %1, %2" : "=v"(r) : "v"(lo), "v"(hi));
  return r;   // .lo16 = bf16(lo), .hi16 = bf16(hi), RNE — matches f2bf
}

__device__ __forceinline__ void glds16(const void* g, void* l) {
  __builtin_amdgcn_global_load_lds(
      (const __attribute__((address_space(1))) unsigned int*)g,
      (__attribute__((address_space(3))) unsigned int*)l, 16, 0, 0);
}

__device__ __forceinline__ f32x4 fzero4() { f32x4 z = {0.f, 0.f, 0.f, 0.f}; return z; }
__device__ __forceinline__ f32x16 fzero16() {
  f32x16 z;
  #pragma unroll
  for (int i = 0; i < 16; ++i) z[i] = 0.f;
  return z;
}

// ---------------- prep: transpose-convert weights only (x/y cvt folded into gemm) ----------------
__global__ __launch_bounds__(256)
void prep_w_kernel(const float* __restrict__ Wq, const float* __restrict__ Wk,
                   const float* __restrict__ Wv, u16* __restrict__ wt) {
  __shared__ float tile[32][33];
  int t = blockIdx.x;                       // 0..1535
  const float* in; u16* out; int N, tn;
  if (t < 256)      { in = Wq; out = wt;              N = 256;  tn = t; }
  else if (t < 512) { in = Wk; out = wt + 256 * 1024; N = 256;  tn = t - 256; }
  else              { in = Wv; out = wt + 512 * 1024; N = 1024; tn = t - 512; }
  int ntiles = N >> 5;
  int n0 = (tn % ntiles) * 32, k0 = (tn / ntiles) * 32;
  int tx = threadIdx.x & 31, ty = threadIdx.x >> 5;
  #pragma unroll
  for (int j = ty; j < 32; j += 8) tile[j][tx] = in[(size_t)(k0 + j) * N + n0 + tx];
  __syncthreads();
  #pragma unroll
  for (int j = ty; j < 32; j += 8) out[(size_t)(n0 + j) * 1024 + k0 + tx] = f2bf(tile[tx][j]);
}

// ---------------- fused projection GEMM (BK=64, single-buffer, 4 blocks/CU) ------
// A staged DIRECTLY from f32 x/y: float4 loads -> cvt_pk_bf16 -> ds_write_b128
// (XOR-swizzled row ^ (kc<<1) to break the 8-way kc-stride bank conflict; both sides).
// B staged via global_load_lds from pre-transposed bf16 weights.
// out tiles over [8192][1536]: cols 0-255 -> fb (Q, [b][h][m][32]),
// 256-511 -> gb (K, [b][h][nt][kc][128][8]), 512-1535 -> ht (V, [b][h][nt][mc][128][8]).
__global__ __launch_bounds__(256, 4)
void gemm_all_kernel(const float* __restrict__ x, const float* __restrict__ y,
                     const u16* __restrict__ wt,
                     const float* __restrict__ bq, const float* __restrict__ bk,
                     const float* __restrict__ bv,
                     u16* __restrict__ fb, u16* __restrict__ gb, u16* __restrict__ ht) {
  __shared__ __align__(16) u16 ls[17408];   // 34.8 KB: staging (32 KB) / transpose (34.8 KB)
  u16* lA = ls;          // 8192 u16: A tile [kc=8][row=128][8] bf16, rows XOR-swizzled
  u16* lB = ls + 8192;   // 8192 u16: B tile [kc=8][col=128][8]
  const int tid = threadIdx.x, lane = tid & 63;
  const int quad = lane >> 4, l16 = lane & 15;
  const int wave = tid >> 6;

  // XCD-chunked swizzle (768 % 8 == 0 -> bijective): each XCD owns 8 contiguous row-panels
  int lin = blockIdx.x + 12 * blockIdx.y;
  lin = (lin & 7) * 96 + (lin >> 3);
  const int col0 = (lin % 12) * 128, row0 = (lin / 12) * 128;

  const int wm = (wave >> 1) * 64, wn = (wave & 1) * 64;
  const float* Af = (col0 < 256) ? x : y;

  f32x4 acc[4][4];
  #pragma unroll
  for (int i = 0; i < 4; i++)
    #pragma unroll
    for (int j = 0; j < 4; j++) acc[i][j] = fzero4();

  for (int k0 = 0; k0 < 1024; k0 += 64) {
    __syncthreads();
    // A: issue all 8 float4 loads first (vmcnt wait for cvt won't drain B glds)
    float4 a[4][2];
    #pragma unroll
    for (int i = 0; i < 4; i++) {
      int c = i * 256 + tid;
      int row = c >> 3, kc = c & 7;            // 8 lanes/row -> 256B contiguous, coalesced
      const float4* src = (const float4*)(Af + (size_t)(row0 + row) * 1024 + k0 + kc * 8);
      a[i][0] = src[0];
      a[i][1] = src[1];
    }
    // B: async global->LDS (bf16 weights, fragment-ordered)
    #pragma unroll
    for (int i = 0; i < 4; i++) {
      int c = i * 256 + tid;
      glds16(wt + (size_t)(col0 + (c & 127)) * 1024 + k0 + (c >> 7) * 8, lB + c * 8);
    }
    // A: convert + swizzled ds_write
    #pragma unroll
    for (int i = 0; i < 4; i++) {
      int c = i * 256 + tid;
      int row = c >> 3, kc = c & 7;
      u32 w0 = cvt_pk_bf16(a[i][0].x, a[i][0].y);
      u32 w1 = cvt_pk_bf16(a[i][0].z, a[i][0].w);
      u32 w2 = cvt_pk_bf16(a[i][1].x, a[i][1].y);
      u32 w3 = cvt_pk_bf16(a[i][1].z, a[i][1].w);
      *(uint4*)(lA + kc * 1024 + ((row ^ (kc << 1)) * 8)) = make_uint4(w0, w1, w2, w3);
    }
    __syncthreads();
    #pragma unroll
    for (int kk = 0; kk < 2; kk++) {
      bf16x8 af[4], bfr[4];
      const int kc = kk * 4 + quad;
      #pragma unroll
      for (int mi = 0; mi < 4; mi++)
        af[mi] = *(const bf16x8*)(lA + kc * 1024 + (((wm + mi * 16 + l16) ^ (kc << 1)) * 8));
      #pragma unroll
      for (int ni = 0; ni < 4; ni++)
        bfr[ni] = *(const bf16x8*)(lB + (kc * 128 + wn + ni * 16 + l16) * 8);
      #pragma unroll
      for (int mi = 0; mi < 4; mi++)
        #pragma unroll
        for (int ni = 0; ni < 4; ni++)
          acc[mi][ni] = __builtin_amdgcn_mfma_f32_16x16x32_bf16(af[mi], bfr[ni], acc[mi][ni], 0, 0, 0);
    }
  }

  if (col0 < 512) {
    // Q / K epilogue: direct stores, fragment-friendly layouts
    #pragma unroll
    for (int mi = 0; mi < 4; mi++)
      #pragma unroll
      for (int ni = 0; ni < 4; ni++) {
        int col = col0 + wn + ni * 16 + l16;
        float bvv = (col < 256) ? bq[col] : bk[col - 256];
        #pragma unroll
        for (int r = 0; r < 4; r++) {
          int row = row0 + wm + mi * 16 + quad * 4 + r;
          float v = acc[mi][ni][r] + bvv;
          int bb = row >> 11, ml = row & 2047;
          if (col < 256) {
            int h = col >> 5, kk2 = col & 31;
            fb[(((size_t)(bb * 8 + h)) << 16) + ml * 32 + kk2] = f2bf(v);
          } else {
            int c2 = col - 256, h = c2 >> 5, kk2 = c2 & 31;
            gb[((((size_t)(bb * 8 + h)) * 16 + (ml >> 7)) << 12)
               + (kk2 >> 3) * 1024 + (ml & 127) * 8 + (kk2 & 7)] = f2bf(v);
          }
        }
      }
  } else {
    // V epilogue: transpose through LDS, write one contiguous 32KB tile [mc][dv][8]
    const int headblk = (col0 - 512) >> 7;
    const int bb = row0 >> 11, mloc0 = row0 & 2047;
    __syncthreads();  // staging reads done; reuse ls
    #pragma unroll
    for (int mi = 0; mi < 4; mi++)
      #pragma unroll
      for (int ni = 0; ni < 4; ni++) {
        int col = wn + ni * 16 + l16;             // block-local dv
        int rowl = wm + mi * 16 + quad * 4;       // block-local m
        float bvv = bv[(col0 - 512) + col];
        float v0 = acc[mi][ni][0] + bvv, v1 = acc[mi][ni][1] + bvv;
        float v2 = acc[mi][ni][2] + bvv, v3 = acc[mi][ni][3] + bvv;
        *(uint2*)(ls + col * 136 + rowl) =
            make_uint2(pack_bf_trunc(v1, v0), pack_bf_trunc(v3, v2));
      }
    __syncthreads();
    u16* tb = ht + ((((size_t)(bb * 8 + headblk)) * 16 + (mloc0 >> 7)) << 14);
    #pragma unroll
    for (int i = 0; i < 8; ++i) {
      int chunk = i * 256 + tid;                  // [mc=chunk>>7][dv=chunk&127]
      *(uint4*)(tb + chunk * 8) = *(const uint4*)(ls + (chunk & 127) * 136 + (chunk >> 7) * 8);
    }
  }
}

// ---------------- flash attention: 32x32 MFMA, KVBLK=128 (round-4/7 proven), dbuf ----------------
__global__ __launch_bounds__(256, 2)
void attn_kernel(const u16* __restrict__ fb, const u16* __restrict__ gb,
                 const u16* __restrict__ ht, const float* __restrict__ x,
                 const float* __restrict__ gamma, float* __restrict__ out) {
  __shared__ __align__(16) u16 lK[2][4096];    // 2 x 8 KB : K tile [kc=4][n=128][8]
  __shared__ __align__(16) u16 lV[2][16384];   // 2 x 32 KB: V tile [mc=16][dv=128][8]
  const int tid = threadIdx.x;
  const int lane = tid & 63, wave = tid >> 6;
  const int hd = lane >> 5, l31 = lane & 31;

  // XCD-affine swizzle: hw linear id % 8 == head -> each XCD holds 4 (b,head) KV sets (2.56 MB, L2-fit)
  int lin = blockIdx.x + 16 * blockIdx.y + 128 * blockIdx.z;
  const int head = lin & 7;
  const int mblk = (lin >> 3) & 15;
  const int b = lin >> 7;
  const int m0 = mblk * 128;
  const int bh = b * 8 + head;

  const float sscale = 0.17677669529663687f * 1.4426950408889634f;  // 1/sqrt(32)*log2(e)

  // Q fragments: B-frag of mfma(K,Q): lane holds Q[m=l31][k = ks*16 + hd*8 + j]
  const int qrow = m0 + wave * 32 + l31;
  union { bf16x8 v; u16 s[8]; } q0, q1;
  {
    const u16* qp = fb + (((size_t)bh * 2048 + qrow) << 5);
    q0.v = *(const bf16x8*)(qp + hd * 8);
    q1.v = *(const bf16x8*)(qp + 16 + hd * 8);
    #pragma unroll
    for (int j = 0; j < 8; ++j) {
      q0.s[j] = f2bf(__uint_as_float((u32)q0.s[j] << 16) * sscale);
      q1.s[j] = f2bf(__uint_as_float((u32)q1.s[j] << 16) * sscale);
    }
  }

  f32x16 oacc[4];
  #pragma unroll
  for (int i = 0; i < 4; ++i) oacc[i] = fzero16();
  float lsacc[4] = {0.f, 0.f, 0.f, 0.f};       // 4 independent sum chains (static indices)

  const u16* kbase = gb + ((size_t)bh << 16);
  const u16* vbase = ht + ((size_t)bh << 18);

  auto stage = [&](int bufsel, int nt) {
    const u16* ks_ = kbase + ((size_t)nt << 12);
    const u16* vs_ = vbase + ((size_t)nt << 14);
    #pragma unroll
    for (int i = 0; i < 2; ++i) glds16(ks_ + (i * 256 + tid) * 8, &lK[bufsel][(i * 256 + tid) * 8]);
    #pragma unroll
    for (int i = 0; i < 8; ++i) glds16(vs_ + (i * 256 + tid) * 8, &lV[bufsel][(i * 256 + tid) * 8]);
  };

  // one KV-tile (128 n) compute: QK^T -> leaky -> exp2 -> pack -> permlane swap -> PV
  auto compute = [&](const u16* Kc, const u16* Vc) {
    // S^T = K·Q^T per 32-row n-tile; D: col=m=l31, row(n) = (reg&3)+8*(reg>>2)+4*hd
    u32 pk[4][8];
    #pragma unroll
    for (int nt4 = 0; nt4 < 4; ++nt4) {
      bf16x8 k0 = *(const bf16x8*)(Kc + hd * 1024 + (nt4 * 32 + l31) * 8);
      bf16x8 k1 = *(const bf16x8*)(Kc + (2 + hd) * 1024 + (nt4 * 32 + l31) * 8);
      __builtin_amdgcn_s_setprio(1);
      f32x16 s = __builtin_amdgcn_mfma_f32_32x32x16_bf16(k0, q0.v, fzero16(), 0, 0, 0);
      s = __builtin_amdgcn_mfma_f32_32x32x16_bf16(k1, q1.v, s, 0, 0, 0);
      __builtin_amdgcn_s_setprio(0);
      float p[16];
      #pragma unroll
      for (int r = 0; r < 16; ++r) {
        float sv = s[r];
        float lv = fmaxf(sv, 0.2f * sv);            // leaky-relu (scale pre-folded into Q)
        p[r] = __builtin_amdgcn_exp2f(lv);
        lsacc[r & 3] += p[r];                       // 4 parallel dependency chains
      }
      #pragma unroll
      for (int s2 = 0; s2 < 4; ++s2) {              // pack pairs (n even, n odd)
        pk[nt4][s2 * 2 + 0] = pack_bf_trunc(p[s2 * 4 + 1], p[s2 * 4 + 0]);
        pk[nt4][s2 * 2 + 1] = pack_bf_trunc(p[s2 * 4 + 3], p[s2 * 4 + 2]);
      }
    }

    // PV: A-frag P[m=l31][n = kt*16 + hd*8 + j] assembled via v_permlane32_swap_b32 (T12)
    #pragma unroll
    for (int kt = 0; kt < 8; ++kt) {
      const int nt4 = kt >> 1, a = kt & 1;
      u32 w0 = pk[nt4][a * 4 + 0], w1 = pk[nt4][a * 4 + 1];   // s2=2a   pairs (rows 16a+4hd+{0..3})
      u32 w2 = pk[nt4][a * 4 + 2], w3 = pk[nt4][a * 4 + 3];   // s2=2a+1 pairs (rows 16a+8+4hd+{0..3})
      // after swap: w0/w1 = frag words 0/1 (n=16a+8hd+{0..3}), w2/w3 = words 2/3 (+4..7)
      asm("v_permlane32_swap_b32 %0, %1" : "+v"(w0), "+v"(w2));
      asm("v_permlane32_swap_b32 %0, %1" : "+v"(w1), "+v"(w3));
      union { u32 w[4]; bf16x8 v; } pf;
      pf.w[0] = w0; pf.w[1] = w1; pf.w[2] = w2; pf.w[3] = w3;
      __builtin_amdgcn_s_setprio(1);
      #pragma unroll
      for (int dvt = 0; dvt < 4; ++dvt) {
        bf16x8 vf = *(const bf16x8*)(Vc + (kt * 2 + hd) * 1024 + (dvt * 32 + l31) * 8);
        oacc[dvt] = __builtin_amdgcn_mfma_f32_32x32x16_bf16(pf.v, vf, oacc[dvt], 0, 0, 0);
      }
      __builtin_amdgcn_s_setprio(0);
    }
  };

  stage(0, 0);
  __syncthreads();

  #pragma unroll 1
  for (int it = 0; it < 16; it += 2) {
    stage(1, it + 1);                  // prefetch odd tile; drained by barrier below
    compute(&lK[0][0], &lV[0][0]);
    __syncthreads();                   // prefetch landed; buf1 ready
    if (it + 2 < 16) stage(0, it + 2); // prefetch next even tile
    compute(&lK[1][0], &lV[1][0]);
    __syncthreads();
  }

  // row sums: lane holds partial over its n-subset for row m=l31; partner holds the rest
  float lsum = (lsacc[0] + lsacc[1]) + (lsacc[2] + lsacc[3]);
  float ltot = lsum + __shfl_xor(lsum, 32, 64);
  float inv = 1.0f / ltot;
  const float gam = gamma[0];
  const size_t rowbase = ((size_t)(b * 2048 + m0 + wave * 32)) * 1024 + head * 128 + l31;
  #pragma unroll
  for (int reg = 0; reg < 16; ++reg) {
    const int m32 = (reg & 3) + 8 * (reg >> 2) + 4 * hd;
    float iv = __shfl(inv, m32, 64);
    #pragma unroll
    for (int dvt = 0; dvt < 4; ++dvt) {
      size_t idx = rowbase + (size_t)m32 * 1024 + dvt * 32;
      out[idx] = gam * (oacc[dvt][reg] * iv) + x[idx];
    }
  }
}

extern "C" void kernel_launch(void* const* d_in, const int* in_sizes, int n_in,
                              void* d_out, int out_size, void* d_ws, size_t ws_size,
                              hipStream_t stream) {
  const float* x     = (const float*)d_in[0];
  const float* y     = (const float*)d_in[1];
  const float* Wq    = (const float*)d_in[2];
  const float* bq    = (const float*)d_in[3];
  const float* Wk    = (const float*)d_in[4];
  const float* bk    = (const float*)d_in[5];
  const float* Wv    = (const float*)d_in[6];
  const float* bv    = (const float*)d_in[7];
  const float* gamma = (const float*)d_in[8];
  float* out = (float*)d_out;

  char* ws = (char*)d_ws;
  u16* wt = (u16*)(ws + 33554432);      // 3 MB   [1536][1024]  (Wq^T|Wk^T|Wv^T)
  u16* fb = (u16*)(ws + 36700160);      // 4 MB   Q  [b][h][m][32]
  u16* gb = (u16*)(ws + 40894464);      // 4 MB   K  [b][h][nt][kc][128][8]
  u16* ht = (u16*)(ws + 45088768);      // 16 MB  V  [b][h][nt][mc][128][8]

  prep_w_kernel<<<1536, 256, 0, stream>>>(Wq, Wk, Wv, wt);
  gemm_all_kernel<<<dim3(12, 64), 256, 0, stream>>>(x, y, wt, bq, bk, bv, fb, gb, ht);
  attn_kernel<<<dim3(16, 8, 4), 256, 0, stream>>>(fb, gb, ht, x, gamma, out);
}

// Round 9
// 226.308 us; speedup vs baseline: 1.2046x; 1.0347x over previous
//
#include <hip/hip_runtime.h>
#include <cstdint>
#include <cstddef>

typedef unsigned short u16;
typedef unsigned int u32;
typedef __attribute__((ext_vector_type(8))) short bf16x8;
typedef __attribute__((ext_vector_type(4))) float f32x4;
typedef __attribute__((ext_vector_type(16))) float f32x16;

__device__ __forceinline__ u16 f2bf(float f) {
  union { float f; unsigned int u; } v; v.f = f;
  unsigned int r = v.u + 0x7fffu + ((v.u >> 16) & 1u);
  return (u16)(r >> 16);
}

__device__ __forceinline__ u32 pack_bf_trunc(float hi, float lo) {
#if __has_builtin(__builtin_amdgcn_perm)
  return __builtin_amdgcn_perm(__float_as_uint(hi), __float_as_uint(lo), 0x07060302u);
#else
  return (__float_as_uint(hi) & 0xffff0000u) | (__float_as_uint(lo) >> 16);
#endif
}

__device__ __forceinline__ u32 cvt_pk_bf16(float lo, float hi) {
  u32 r;
  asm("v_cvt_pk_bf16_f32 %0, %1, %2" : "=v"(r) : "v"(lo), "v"(hi));
  return r;   // .lo16 = bf16(lo), .hi16 = bf16(hi), RNE — matches f2bf
}

__device__ __forceinline__ void glds16(const void* g, void* l) {
  __builtin_amdgcn_global_load_lds(
      (const __attribute__((address_space(1))) unsigned int*)g,
      (__attribute__((address_space(3))) unsigned int*)l, 16, 0, 0);
}

__device__ __forceinline__ f32x4 fzero4() { f32x4 z = {0.f, 0.f, 0.f, 0.f}; return z; }
__device__ __forceinline__ f32x16 fzero16() {
  f32x16 z;
  #pragma unroll
  for (int i = 0; i < 16; ++i) z[i] = 0.f;
  return z;
}

// ---------------- prep: transpose-convert weights only (x/y cvt folded into gemm) ----------------
__global__ __launch_bounds__(256)
void prep_w_kernel(const float* __restrict__ Wq, const float* __restrict__ Wk,
                   const float* __restrict__ Wv, u16* __restrict__ wt) {
  __shared__ float tile[32][33];
  int t = blockIdx.x;                       // 0..1535
  const float* in; u16* out; int N, tn;
  if (t < 256)      { in = Wq; out = wt;              N = 256;  tn = t; }
  else if (t < 512) { in = Wk; out = wt + 256 * 1024; N = 256;  tn = t - 256; }
  else              { in = Wv; out = wt + 512 * 1024; N = 1024; tn = t - 512; }
  int ntiles = N >> 5;
  int n0 = (tn % ntiles) * 32, k0 = (tn / ntiles) * 32;
  int tx = threadIdx.x & 31, ty = threadIdx.x >> 5;
  #pragma unroll
  for (int j = ty; j < 32; j += 8) tile[j][tx] = in[(size_t)(k0 + j) * N + n0 + tx];
  __syncthreads();
  #pragma unroll
  for (int j = ty; j < 32; j += 8) out[(size_t)(n0 + j) * 1024 + k0 + tx] = f2bf(tile[tx][j]);
}

// ---------------- fused projection GEMM (BK=64, A-reg pipeline, 3 blocks/CU) ------
// A staged from f32 x/y with a register pipeline (T14): A(k+1) loads issued BEFORE the
// pre-compute barrier so their latency drains merged with B(k)'s glds wait; the cvt +
// swizzled ds_write at iter k+1 consumes already-landed regs.
// B staged via global_load_lds from pre-transposed bf16 weights.
// out tiles over [8192][1536]: cols 0-255 -> fb (Q), 256-511 -> gb (K), 512-1535 -> ht (V).
__global__ __launch_bounds__(256, 3)
void gemm_all_kernel(const float* __restrict__ x, const float* __restrict__ y,
                     const u16* __restrict__ wt,
                     const float* __restrict__ bq, const float* __restrict__ bk,
                     const float* __restrict__ bv,
                     u16* __restrict__ fb, u16* __restrict__ gb, u16* __restrict__ ht) {
  __shared__ __align__(16) u16 ls[17408];   // 34.8 KB: staging (32 KB) / transpose (34.8 KB)
  u16* lA = ls;          // 8192 u16: A tile [kc=8][row=128][8] bf16, rows XOR-swizzled
  u16* lB = ls + 8192;   // 8192 u16: B tile [kc=8][col=128][8]
  const int tid = threadIdx.x, lane = tid & 63;
  const int quad = lane >> 4, l16 = lane & 15;
  const int wave = tid >> 6;

  // XCD-chunked swizzle (768 % 8 == 0 -> bijective): each XCD owns 8 contiguous row-panels
  int lin = blockIdx.x + 12 * blockIdx.y;
  lin = (lin & 7) * 96 + (lin >> 3);
  const int col0 = (lin % 12) * 128, row0 = (lin / 12) * 128;

  const int wm = (wave >> 1) * 64, wn = (wave & 1) * 64;
  const float* Af = (col0 < 256) ? x : y;

  f32x4 acc[4][4];
  #pragma unroll
  for (int i = 0; i < 4; i++)
    #pragma unroll
    for (int j = 0; j < 4; j++) acc[i][j] = fzero4();

  // per-thread A chunk geometry: row = c>>3 (coalesced 256B rows), kc = c&7
  float4 a[4][2];
  #pragma unroll
  for (int i = 0; i < 4; i++) {              // prologue: A(0) -> regs
    int c = i * 256 + tid;
    const float4* src = (const float4*)(Af + (size_t)(row0 + (c >> 3)) * 1024 + (c & 7) * 8);
    a[i][0] = src[0];
    a[i][1] = src[1];
  }

  for (int k0 = 0; k0 < 1024; k0 += 64) {
    __syncthreads();                         // previous compute done reading lA/lB
    // A(k0): cvt from regs + swizzled ds_write (regs landed during previous compute)
    #pragma unroll
    for (int i = 0; i < 4; i++) {
      int c = i * 256 + tid;
      int row = c >> 3, kc = c & 7;
      u32 w0 = cvt_pk_bf16(a[i][0].x, a[i][0].y);
      u32 w1 = cvt_pk_bf16(a[i][0].z, a[i][0].w);
      u32 w2 = cvt_pk_bf16(a[i][1].x, a[i][1].y);
      u32 w3 = cvt_pk_bf16(a[i][1].z, a[i][1].w);
      *(uint4*)(lA + kc * 1024 + ((row ^ (kc << 1)) * 8)) = make_uint4(w0, w1, w2, w3);
    }
    // B(k0): async global->LDS (bf16 weights, fragment-ordered)
    #pragma unroll
    for (int i = 0; i < 4; i++) {
      int c = i * 256 + tid;
      glds16(wt + (size_t)(col0 + (c & 127)) * 1024 + k0 + (c >> 7) * 8, lB + c * 8);
    }
    // A(k0+64) prefetch -> regs; drains together with B at the barrier below
    if (k0 < 960) {
      #pragma unroll
      for (int i = 0; i < 4; i++) {
        int c = i * 256 + tid;
        const float4* src =
            (const float4*)(Af + (size_t)(row0 + (c >> 3)) * 1024 + (k0 + 64) + (c & 7) * 8);
        a[i][0] = src[0];
        a[i][1] = src[1];
      }
    }
    __syncthreads();                         // drains B glds + A prefetch + ds_writes
    #pragma unroll
    for (int kk = 0; kk < 2; kk++) {
      bf16x8 af[4], bfr[4];
      const int kc = kk * 4 + quad;
      #pragma unroll
      for (int mi = 0; mi < 4; mi++)
        af[mi] = *(const bf16x8*)(lA + kc * 1024 + (((wm + mi * 16 + l16) ^ (kc << 1)) * 8));
      #pragma unroll
      for (int ni = 0; ni < 4; ni++)
        bfr[ni] = *(const bf16x8*)(lB + (kc * 128 + wn + ni * 16 + l16) * 8);
      #pragma unroll
      for (int mi = 0; mi < 4; mi++)
        #pragma unroll
        for (int ni = 0; ni < 4; ni++)
          acc[mi][ni] = __builtin_amdgcn_mfma_f32_16x16x32_bf16(af[mi], bfr[ni], acc[mi][ni], 0, 0, 0);
    }
  }

  if (col0 < 512) {
    // Q / K epilogue: direct stores, fragment-friendly layouts
    #pragma unroll
    for (int mi = 0; mi < 4; mi++)
      #pragma unroll
      for (int ni = 0; ni < 4; ni++) {
        int col = col0 + wn + ni * 16 + l16;
        float bvv = (col < 256) ? bq[col] : bk[col - 256];
        #pragma unroll
        for (int r = 0; r < 4; r++) {
          int row = row0 + wm + mi * 16 + quad * 4 + r;
          float v = acc[mi][ni][r] + bvv;
          int bb = row >> 11, ml = row & 2047;
          if (col < 256) {
            int h = col >> 5, kk2 = col & 31;
            fb[(((size_t)(bb * 8 + h)) << 16) + ml * 32 + kk2] = f2bf(v);
          } else {
            int c2 = col - 256, h = c2 >> 5, kk2 = c2 & 31;
            gb[((((size_t)(bb * 8 + h)) * 16 + (ml >> 7)) << 12)
               + (kk2 >> 3) * 1024 + (ml & 127) * 8 + (kk2 & 7)] = f2bf(v);
          }
        }
      }
  } else {
    // V epilogue: transpose through LDS, write one contiguous 32KB tile [mc][dv][8]
    const int headblk = (col0 - 512) >> 7;
    const int bb = row0 >> 11, mloc0 = row0 & 2047;
    __syncthreads();  // staging reads done; reuse ls
    #pragma unroll
    for (int mi = 0; mi < 4; mi++)
      #pragma unroll
      for (int ni = 0; ni < 4; ni++) {
        int col = wn + ni * 16 + l16;             // block-local dv
        int rowl = wm + mi * 16 + quad * 4;       // block-local m
        float bvv = bv[(col0 - 512) + col];
        float v0 = acc[mi][ni][0] + bvv, v1 = acc[mi][ni][1] + bvv;
        float v2 = acc[mi][ni][2] + bvv, v3 = acc[mi][ni][3] + bvv;
        *(uint2*)(ls + col * 136 + rowl) =
            make_uint2(pack_bf_trunc(v1, v0), pack_bf_trunc(v3, v2));
      }
    __syncthreads();
    u16* tb = ht + ((((size_t)(bb * 8 + headblk)) * 16 + (mloc0 >> 7)) << 14);
    #pragma unroll
    for (int i = 0; i < 8; ++i) {
      int chunk = i * 256 + tid;                  // [mc=chunk>>7][dv=chunk&127]
      *(uint4*)(tb + chunk * 8) = *(const uint4*)(ls + (chunk & 127) * 136 + (chunk >> 7) * 8);
    }
  }
}

// ---------------- flash attention: 32x32 MFMA, KVBLK=128 (round-4/7 proven), dbuf ----------------
__global__ __launch_bounds__(256, 2)
void attn_kernel(const u16* __restrict__ fb, const u16* __restrict__ gb,
                 const u16* __restrict__ ht, const float* __restrict__ x,
                 const float* __restrict__ gamma, float* __restrict__ out) {
  __shared__ __align__(16) u16 lK[2][4096];    // 2 x 8 KB : K tile [kc=4][n=128][8]
  __shared__ __align__(16) u16 lV[2][16384];   // 2 x 32 KB: V tile [mc=16][dv=128][8]
  const int tid = threadIdx.x;
  const int lane = tid & 63, wave = tid >> 6;
  const int hd = lane >> 5, l31 = lane & 31;

  // XCD-affine swizzle: hw linear id % 8 == head -> each XCD holds 4 (b,head) KV sets (2.56 MB, L2-fit)
  int lin = blockIdx.x + 16 * blockIdx.y + 128 * blockIdx.z;
  const int head = lin & 7;
  const int mblk = (lin >> 3) & 15;
  const int b = lin >> 7;
  const int m0 = mblk * 128;
  const int bh = b * 8 + head;

  const float sscale = 0.17677669529663687f * 1.4426950408889634f;  // 1/sqrt(32)*log2(e)

  // Q fragments: B-frag of mfma(K,Q): lane holds Q[m=l31][k = ks*16 + hd*8 + j]
  const int qrow = m0 + wave * 32 + l31;
  union { bf16x8 v; u16 s[8]; } q0, q1;
  {
    const u16* qp = fb + (((size_t)bh * 2048 + qrow) << 5);
    q0.v = *(const bf16x8*)(qp + hd * 8);
    q1.v = *(const bf16x8*)(qp + 16 + hd * 8);
    #pragma unroll
    for (int j = 0; j < 8; ++j) {
      q0.s[j] = f2bf(__uint_as_float((u32)q0.s[j] << 16) * sscale);
      q1.s[j] = f2bf(__uint_as_float((u32)q1.s[j] << 16) * sscale);
    }
  }

  f32x16 oacc[4];
  #pragma unroll
  for (int i = 0; i < 4; ++i) oacc[i] = fzero16();
  float lsacc[4] = {0.f, 0.f, 0.f, 0.f};       // 4 independent sum chains (static indices)

  const u16* kbase = gb + ((size_t)bh << 16);
  const u16* vbase = ht + ((size_t)bh << 18);

  auto stage = [&](int bufsel, int nt) {
    const u16* ks_ = kbase + ((size_t)nt << 12);
    const u16* vs_ = vbase + ((size_t)nt << 14);
    #pragma unroll
    for (int i = 0; i < 2; ++i) glds16(ks_ + (i * 256 + tid) * 8, &lK[bufsel][(i * 256 + tid) * 8]);
    #pragma unroll
    for (int i = 0; i < 8; ++i) glds16(vs_ + (i * 256 + tid) * 8, &lV[bufsel][(i * 256 + tid) * 8]);
  };

  // one KV-tile (128 n) compute: QK^T -> leaky -> exp2 -> pack -> permlane swap -> PV
  auto compute = [&](const u16* Kc, const u16* Vc) {
    // S^T = K·Q^T per 32-row n-tile; D: col=m=l31, row(n) = (reg&3)+8*(reg>>2)+4*hd
    u32 pk[4][8];
    #pragma unroll
    for (int nt4 = 0; nt4 < 4; ++nt4) {
      bf16x8 k0 = *(const bf16x8*)(Kc + hd * 1024 + (nt4 * 32 + l31) * 8);
      bf16x8 k1 = *(const bf16x8*)(Kc + (2 + hd) * 1024 + (nt4 * 32 + l31) * 8);
      __builtin_amdgcn_s_setprio(1);
      f32x16 s = __builtin_amdgcn_mfma_f32_32x32x16_bf16(k0, q0.v, fzero16(), 0, 0, 0);
      s = __builtin_amdgcn_mfma_f32_32x32x16_bf16(k1, q1.v, s, 0, 0, 0);
      __builtin_amdgcn_s_setprio(0);
      float p[16];
      #pragma unroll
      for (int r = 0; r < 16; ++r) {
        float sv = s[r];
        float lv = fmaxf(sv, 0.2f * sv);            // leaky-relu (scale pre-folded into Q)
        p[r] = __builtin_amdgcn_exp2f(lv);
        lsacc[r & 3] += p[r];                       // 4 parallel dependency chains
      }
      #pragma unroll
      for (int s2 = 0; s2 < 4; ++s2) {              // pack pairs (n even, n odd)
        pk[nt4][s2 * 2 + 0] = pack_bf_trunc(p[s2 * 4 + 1], p[s2 * 4 + 0]);
        pk[nt4][s2 * 2 + 1] = pack_bf_trunc(p[s2 * 4 + 3], p[s2 * 4 + 2]);
      }
    }

    // PV: A-frag P[m=l31][n = kt*16 + hd*8 + j] assembled via v_permlane32_swap_b32 (T12)
    #pragma unroll
    for (int kt = 0; kt < 8; ++kt) {
      const int nt4 = kt >> 1, a = kt & 1;
      u32 w0 = pk[nt4][a * 4 + 0], w1 = pk[nt4][a * 4 + 1];   // s2=2a   pairs (rows 16a+4hd+{0..3})
      u32 w2 = pk[nt4][a * 4 + 2], w3 = pk[nt4][a * 4 + 3];   // s2=2a+1 pairs (rows 16a+8+4hd+{0..3})
      // after swap: w0/w1 = frag words 0/1 (n=16a+8hd+{0..3}), w2/w3 = words 2/3 (+4..7)
      asm("v_permlane32_swap_b32 %0, %1" : "+v"(w0), "+v"(w2));
      asm("v_permlane32_swap_b32 %0, %1" : "+v"(w1), "+v"(w3));
      union { u32 w[4]; bf16x8 v; } pf;
      pf.w[0] = w0; pf.w[1] = w1; pf.w[2] = w2; pf.w[3] = w3;
      __builtin_amdgcn_s_setprio(1);
      #pragma unroll
      for (int dvt = 0; dvt < 4; ++dvt) {
        bf16x8 vf = *(const bf16x8*)(Vc + (kt * 2 + hd) * 1024 + (dvt * 32 + l31) * 8);
        oacc[dvt] = __builtin_amdgcn_mfma_f32_32x32x16_bf16(pf.v, vf, oacc[dvt], 0, 0, 0);
      }
      __builtin_amdgcn_s_setprio(0);
    }
  };

  stage(0, 0);
  __syncthreads();

  #pragma unroll 1
  for (int it = 0; it < 16; it += 2) {
    stage(1, it + 1);                  // prefetch odd tile; drained by barrier below
    compute(&lK[0][0], &lV[0][0]);
    __syncthreads();                   // prefetch landed; buf1 ready
    if (it + 2 < 16) stage(0, it + 2); // prefetch next even tile
    compute(&lK[1][0], &lV[1][0]);
    __syncthreads();
  }

  // row sums: lane holds partial over its n-subset for row m=l31; partner holds the rest
  float lsum = (lsacc[0] + lsacc[1]) + (lsacc[2] + lsacc[3]);
  float ltot = lsum + __shfl_xor(lsum, 32, 64);
  float inv = 1.0f / ltot;
  const float gam = gamma[0];
  const size_t rowbase = ((size_t)(b * 2048 + m0 + wave * 32)) * 1024 + head * 128 + l31;
  #pragma unroll
  for (int reg = 0; reg < 16; ++reg) {
    const int m32 = (reg & 3) + 8 * (reg >> 2) + 4 * hd;
    float iv = __shfl(inv, m32, 64);
    #pragma unroll
    for (int dvt = 0; dvt < 4; ++dvt) {
      size_t idx = rowbase + (size_t)m32 * 1024 + dvt * 32;
      out[idx] = gam * (oacc[dvt][reg] * iv) + x[idx];
    }
  }
}

extern "C" void kernel_launch(void* const* d_in, const int* in_sizes, int n_in,
                              void* d_out, int out_size, void* d_ws, size_t ws_size,
                              hipStream_t stream) {
  const float* x     = (const float*)d_in[0];
  const float* y     = (const float*)d_in[1];
  const float* Wq    = (const float*)d_in[2];
  const float* bq    = (const float*)d_in[3];
  const float* Wk    = (const float*)d_in[4];
  const float* bk    = (const float*)d_in[5];
  const float* Wv    = (const float*)d_in[6];
  const float* bv    = (const float*)d_in[7];
  const float* gamma = (const float*)d_in[8];
  float* out = (float*)d_out;

  char* ws = (char*)d_ws;
  u16* wt = (u16*)(ws + 33554432);      // 3 MB   [1536][1024]  (Wq^T|Wk^T|Wv^T)
  u16* fb = (u16*)(ws + 36700160);      // 4 MB   Q  [b][h][m][32]
  u16* gb = (u16*)(ws + 40894464);      // 4 MB   K  [b][h][nt][kc][128][8]
  u16* ht = (u16*)(ws + 45088768);      // 16 MB  V  [b][h][nt][mc][128][8]

  prep_w_kernel<<<1536, 256, 0, stream>>>(Wq, Wk, Wv, wt);
  gemm_all_kernel<<<dim3(12, 64), 256, 0, stream>>>(x, y, wt, bq, bk, bv, fb, gb, ht);
  attn_kernel<<<dim3(16, 8, 4), 256, 0, stream>>>(fb, gb, ht, x, gamma, out);
}